// Round 2
// baseline (3633.833 us; speedup 1.0000x reference)
//
#include <hip/hip_runtime.h>
#include <stdint.h>

#define NN 20000
#define EE 600000
#define HH 128
#define LL 6
#define BBATCH 16
#define VV 4

typedef __bf16 bf16x8 __attribute__((ext_vector_type(8)));
typedef float f32x4 __attribute__((ext_vector_type(4)));

__device__ __forceinline__ float bf2f(unsigned short u) {
    union { uint32_t i; float f; } v; v.i = ((uint32_t)u) << 16; return v.f;
}
__device__ __forceinline__ unsigned short f2bf(float f) {
    union { float f; uint32_t i; } v; v.f = f;
    uint32_t u = v.i;
    return (unsigned short)((u + 0x7FFFu + ((u >> 16) & 1u)) >> 16);
}
// dual-world scalar load: f==1 -> f32 buffer, f==0 -> bf16 buffer
__device__ __forceinline__ float loadf(const void* p, size_t i, int f) {
    return f ? ((const float*)p)[i] : bf2f(((const unsigned short*)p)[i]);
}
// dual-world load of 8 consecutive elements as bf16
__device__ __forceinline__ void load8bf(const void* base, size_t elem, int f, unsigned short* o) {
    if (!f) {
        *(uint4*)o = *(const uint4*)((const unsigned short*)base + elem);
    } else {
        const float* p = (const float*)base + elem;
        float4 a = *(const float4*)p, b = *(const float4*)(p + 4);
        o[0] = f2bf(a.x); o[1] = f2bf(a.y); o[2] = f2bf(a.z); o[3] = f2bf(a.w);
        o[4] = f2bf(b.x); o[5] = f2bf(b.y); o[6] = f2bf(b.z); o[7] = f2bf(b.w);
    }
}

// ---- dtype sniffer: bf16 h_V ~N(0,1) -> ~100% plausible u16s; f32 -> ~67% ----
__global__ void detect_kernel(const void* hv, int* flag) {
    __shared__ int cnt;
    if (threadIdx.x == 0) cnt = 0;
    __syncthreads();
    const unsigned short* u = (const unsigned short*)hv;
    int local = 0;
    for (int i = threadIdx.x; i < 4096; i += 256) {
        unsigned short v = u[i];
        int e = (v >> 7) & 0xFF;
        if ((v & 0x7FFF) == 0 || (e >= 0x30 && e <= 0x85)) local++;
    }
    atomicAdd(&cnt, local);
    __syncthreads();
    if (threadIdx.x == 0) flag[0] = (cnt < 3500) ? 1 : 0;  // 1 = f32 world
}

// ---------------- weight repack: [K][N] -> [K/32][N][32] per layer (to bf16) ----------------
__global__ void repack_kernel(const void* __restrict__ src,
                              unsigned short* __restrict__ dst,
                              int K, int Nc, int total, const int* __restrict__ flag) {
    int idx = blockIdx.x * blockDim.x + threadIdx.x;
    if (idx >= total) return;
    const int f = flag[0];
    int per = K * Nc;
    int layer = idx / per, rem = idx % per;
    int k = rem / Nc, n = rem % Nc;
    dst[(size_t)layer * per + ((size_t)(k >> 5) * Nc + n) * 32 + (k & 31)] = f2bf(loadf(src, idx, f));
}

__global__ void init_hv_kernel(const void* __restrict__ hv_in,
                               float* __restrict__ hv_f32,
                               unsigned short* __restrict__ hv_bf, int total,
                               const int* __restrict__ flag) {
    int idx = blockIdx.x * blockDim.x + threadIdx.x;
    if (idx >= total) return;
    const int f = flag[0];
    float v = loadf(hv_in, idx, f);
    hv_bf[idx] = f2bf(v);
    hv_f32[idx] = v;
}

__global__ void deg_kernel(const int* __restrict__ Eidx, float* __restrict__ deg) {
    int e = blockIdx.x * blockDim.x + threadIdx.x;
    if (e < EE) atomicAdd(&deg[Eidx[e]], 1.0f);
}

// ---------------- edge MLP + scatter-add ----------------
__launch_bounds__(256, 3)
__global__ void edge_kernel(const void* __restrict__ hE,
                            const unsigned short* __restrict__ hv_bf,
                            const int* __restrict__ Eidx,
                            const unsigned short* __restrict__ W1p, const void* __restrict__ b1,
                            const unsigned short* __restrict__ W2p, const void* __restrict__ b2,
                            const unsigned short* __restrict__ W3p, const void* __restrict__ b3,
                            float* __restrict__ agg, int layer, const int* __restrict__ flag) {
    __shared__ __align__(16) unsigned short ev[64 * 392];   // h_EV tile [64][384] pad->392
    unsigned short* m1 = ev;             // [64][136] overlay
    unsigned short* m2 = ev + 64 * 136;  // [64][136]

    const int t = threadIdx.x;
    const int w = t >> 6;
    const int lane = t & 63;
    const int q = lane >> 4, ln = lane & 15;
    const int e0 = blockIdx.x * 64;
    const int f = flag[0];

    // ---- stage h_EV = [h_E | h_V[src] | h_V[dst]] ----
    for (int c = t; c < 1024; c += 256) {
        int row = c >> 4, p = c & 15;
        int e = e0 + row;
        unsigned short tmp[8];
        load8bf(hE, (size_t)e * 128 + p * 8, f, tmp);
        *(uint4*)&ev[row * 392 + p * 8] = *(uint4*)tmp;
    }
    for (int c = t; c < 1024; c += 256) {
        int row = c >> 4, p = c & 15;
        int e = e0 + row;
        int s = Eidx[e];
        *(uint4*)&ev[row * 392 + 128 + p * 8] = *(const uint4*)&hv_bf[(size_t)s * 128 + p * 8];
    }
    for (int c = t; c < 1024; c += 256) {
        int row = c >> 4, p = c & 15;
        int e = e0 + row;
        int d = Eidx[EE + e];
        *(uint4*)&ev[row * 392 + 256 + p * 8] = *(const uint4*)&hv_bf[(size_t)d * 128 + p * 8];
    }
    __syncthreads();

    f32x4 acc[4][2];

    // ---- GEMM1: [64,384]@[384,128] ----
    {
        const unsigned short* W1l = W1p + (size_t)layer * 384 * 128;
        for (int c = 0; c < 2; c++) {
            float bv = loadf(b1, (size_t)layer * HH + 16 * (2 * w + c) + ln, f);
            for (int rt = 0; rt < 4; rt++) acc[rt][c] = (f32x4){bv, bv, bv, bv};
        }
        for (int kk = 0; kk < 12; kk++) {
            bf16x8 bfr[2];
            for (int c = 0; c < 2; c++)
                bfr[c] = *(const bf16x8*)&W1l[((size_t)(kk * 128 + 16 * (2 * w + c) + ln)) * 32 + q * 8];
            for (int rt = 0; rt < 4; rt++) {
                bf16x8 af = *(bf16x8*)&ev[(16 * rt + ln) * 392 + kk * 32 + q * 8];
                acc[rt][0] = __builtin_amdgcn_mfma_f32_16x16x32_bf16(af, bfr[0], acc[rt][0], 0, 0, 0);
                acc[rt][1] = __builtin_amdgcn_mfma_f32_16x16x32_bf16(af, bfr[1], acc[rt][1], 0, 0, 0);
            }
        }
    }
    __syncthreads();  // done reading ev
    for (int rt = 0; rt < 4; rt++)
        for (int c = 0; c < 2; c++)
            for (int r = 0; r < 4; r++) {
                float v = acc[rt][c][r]; v = v > 0.f ? v : 0.f;
                m1[(16 * rt + q * 4 + r) * 136 + 16 * (2 * w + c) + ln] = f2bf(v);
            }
    __syncthreads();

    // ---- GEMM2: [64,128]@[128,128] + relu -> m2 ----
    {
        const unsigned short* W2l = W2p + (size_t)layer * 128 * 128;
        for (int c = 0; c < 2; c++) {
            float bv = loadf(b2, (size_t)layer * HH + 16 * (2 * w + c) + ln, f);
            for (int rt = 0; rt < 4; rt++) acc[rt][c] = (f32x4){bv, bv, bv, bv};
        }
        for (int kk = 0; kk < 4; kk++) {
            bf16x8 bfr[2];
            for (int c = 0; c < 2; c++)
                bfr[c] = *(const bf16x8*)&W2l[((size_t)(kk * 128 + 16 * (2 * w + c) + ln)) * 32 + q * 8];
            for (int rt = 0; rt < 4; rt++) {
                bf16x8 af = *(bf16x8*)&m1[(16 * rt + ln) * 136 + kk * 32 + q * 8];
                acc[rt][0] = __builtin_amdgcn_mfma_f32_16x16x32_bf16(af, bfr[0], acc[rt][0], 0, 0, 0);
                acc[rt][1] = __builtin_amdgcn_mfma_f32_16x16x32_bf16(af, bfr[1], acc[rt][1], 0, 0, 0);
            }
        }
    }
    for (int rt = 0; rt < 4; rt++)
        for (int c = 0; c < 2; c++)
            for (int r = 0; r < 4; r++) {
                float v = acc[rt][c][r]; v = v > 0.f ? v : 0.f;
                m2[(16 * rt + q * 4 + r) * 136 + 16 * (2 * w + c) + ln] = f2bf(v);
            }
    __syncthreads();

    // ---- GEMM3: [64,128]@[128,128] (no relu) ----
    {
        const unsigned short* W3l = W3p + (size_t)layer * 128 * 128;
        for (int c = 0; c < 2; c++) {
            float bv = loadf(b3, (size_t)layer * HH + 16 * (2 * w + c) + ln, f);
            for (int rt = 0; rt < 4; rt++) acc[rt][c] = (f32x4){bv, bv, bv, bv};
        }
        for (int kk = 0; kk < 4; kk++) {
            bf16x8 bfr[2];
            for (int c = 0; c < 2; c++)
                bfr[c] = *(const bf16x8*)&W3l[((size_t)(kk * 128 + 16 * (2 * w + c) + ln)) * 32 + q * 8];
            for (int rt = 0; rt < 4; rt++) {
                bf16x8 af = *(bf16x8*)&m2[(16 * rt + ln) * 136 + kk * 32 + q * 8];
                acc[rt][0] = __builtin_amdgcn_mfma_f32_16x16x32_bf16(af, bfr[0], acc[rt][0], 0, 0, 0);
                acc[rt][1] = __builtin_amdgcn_mfma_f32_16x16x32_bf16(af, bfr[1], acc[rt][1], 0, 0, 0);
            }
        }
    }

    // ---- scatter-add into agg[src] ----
    for (int rt = 0; rt < 4; rt++) {
        int se[4];
        for (int r = 0; r < 4; r++) se[r] = Eidx[e0 + 16 * rt + q * 4 + r];
        for (int c = 0; c < 2; c++) {
            int col = 16 * (2 * w + c) + ln;
            for (int r = 0; r < 4; r++)
                atomicAdd(&agg[(size_t)se[r] * HH + col], acc[rt][c][r]);
        }
    }
}

// ---------------- node update: LN1 -> FFN -> LN2 ----------------
__launch_bounds__(256, 1)
__global__ void node_kernel(float* __restrict__ hv_f32, unsigned short* __restrict__ hv_bf,
                            const float* __restrict__ agg, const float* __restrict__ deg,
                            const void* __restrict__ ln1g, const void* __restrict__ ln1b,
                            const unsigned short* __restrict__ Wip, const void* __restrict__ bip,
                            const unsigned short* __restrict__ Wop, const void* __restrict__ bop,
                            const void* __restrict__ ln2g, const void* __restrict__ ln2b,
                            int layer, const int* __restrict__ flag) {
    __shared__ __align__(16) float xf[64 * 132];
    __shared__ __align__(16) unsigned short tb[64 * 136];
    __shared__ __align__(16) unsigned short ub[64 * 520];
    const int t = threadIdx.x;
    const int w = t >> 6;
    const int lane = t & 63;
    const int q = lane >> 4, ln = lane & 15;
    const int n0 = blockIdx.x * 64;
    const int f = flag[0];

    for (int idx = t; idx < 64 * 128; idx += 256) {
        int row = idx >> 7, col = idx & 127;
        int g = n0 + row;
        float v = 0.f;
        if (g < NN) {
            float dg = deg[g]; dg = dg < 1.f ? 1.f : dg;
            v = hv_f32[(size_t)g * 128 + col] + agg[(size_t)g * 128 + col] / dg;
        }
        xf[row * 132 + col] = v;
    }
    __syncthreads();

    if (t < 64) {
        float mu = 0.f;
        for (int j = 0; j < 128; j++) mu += xf[t * 132 + j];
        mu *= (1.f / 128.f);
        float var = 0.f;
        for (int j = 0; j < 128; j++) { float d = xf[t * 132 + j] - mu; var += d * d; }
        var *= (1.f / 128.f);
        float rs = rsqrtf(var + 1e-5f);
        for (int j = 0; j < 128; j++) {
            float val = (xf[t * 132 + j] - mu) * rs * loadf(ln1g, layer * 128 + j, f)
                        + loadf(ln1b, layer * 128 + j, f);
            xf[t * 132 + j] = val;
            tb[t * 136 + j] = f2bf(val);
        }
    }
    __syncthreads();

    // GEMM Wi: [64,128]@[128,512] + relu -> ub
    {
        const unsigned short* Wil = Wip + (size_t)layer * 128 * 512;
        for (int g2 = 0; g2 < 2; g2++) {
            f32x4 acc[4][4];
            for (int c = 0; c < 4; c++) {
                int ct = 8 * w + 4 * g2 + c;
                float bv = loadf(bip, (size_t)layer * 512 + 16 * ct + ln, f);
                for (int rt = 0; rt < 4; rt++) acc[rt][c] = (f32x4){bv, bv, bv, bv};
            }
            for (int kk = 0; kk < 4; kk++) {
                bf16x8 bfr[4];
                for (int c = 0; c < 4; c++) {
                    int ct = 8 * w + 4 * g2 + c;
                    bfr[c] = *(const bf16x8*)&Wil[((size_t)(kk * 512 + 16 * ct + ln)) * 32 + q * 8];
                }
                for (int rt = 0; rt < 4; rt++) {
                    bf16x8 af = *(bf16x8*)&tb[(16 * rt + ln) * 136 + kk * 32 + q * 8];
                    for (int c = 0; c < 4; c++)
                        acc[rt][c] = __builtin_amdgcn_mfma_f32_16x16x32_bf16(af, bfr[c], acc[rt][c], 0, 0, 0);
                }
            }
            for (int rt = 0; rt < 4; rt++)
                for (int c = 0; c < 4; c++) {
                    int ct = 8 * w + 4 * g2 + c;
                    for (int r = 0; r < 4; r++) {
                        float v = acc[rt][c][r]; v = v > 0.f ? v : 0.f;
                        ub[(16 * rt + q * 4 + r) * 520 + 16 * ct + ln] = f2bf(v);
                    }
                }
        }
    }
    __syncthreads();

    // GEMM Wo: [64,512]@[512,128] ; add into xf
    {
        const unsigned short* Wol = Wop + (size_t)layer * 512 * 128;
        f32x4 acc[4][2];
        for (int c = 0; c < 2; c++) {
            int ct = 2 * w + c;
            float bv = loadf(bop, (size_t)layer * 128 + 16 * ct + ln, f);
            for (int rt = 0; rt < 4; rt++) acc[rt][c] = (f32x4){bv, bv, bv, bv};
        }
        for (int kk = 0; kk < 16; kk++) {
            bf16x8 bfr[2];
            for (int c = 0; c < 2; c++) {
                int ct = 2 * w + c;
                bfr[c] = *(const bf16x8*)&Wol[((size_t)(kk * 128 + 16 * ct + ln)) * 32 + q * 8];
            }
            for (int rt = 0; rt < 4; rt++) {
                bf16x8 af = *(bf16x8*)&ub[(16 * rt + ln) * 520 + kk * 32 + q * 8];
                for (int c = 0; c < 2; c++)
                    acc[rt][c] = __builtin_amdgcn_mfma_f32_16x16x32_bf16(af, bfr[c], acc[rt][c], 0, 0, 0);
            }
        }
        for (int rt = 0; rt < 4; rt++)
            for (int c = 0; c < 2; c++) {
                int ct = 2 * w + c;
                for (int r = 0; r < 4; r++)
                    xf[(16 * rt + q * 4 + r) * 132 + 16 * ct + ln] += acc[rt][c][r];
            }
    }
    __syncthreads();

    if (t < 64) {
        int g = n0 + t;
        if (g < NN) {
            float mu = 0.f;
            for (int j = 0; j < 128; j++) mu += xf[t * 132 + j];
            mu *= (1.f / 128.f);
            float var = 0.f;
            for (int j = 0; j < 128; j++) { float d = xf[t * 132 + j] - mu; var += d * d; }
            var *= (1.f / 128.f);
            float rs = rsqrtf(var + 1e-5f);
            for (int j = 0; j < 128; j++) {
                float val = (xf[t * 132 + j] - mu) * rs * loadf(ln2g, layer * 128 + j, f)
                            + loadf(ln2b, layer * 128 + j, f);
                hv_f32[(size_t)g * 128 + j] = val;
                hv_bf[(size_t)g * 128 + j] = f2bf(val);
            }
        }
    }
}

// ---------------- pooling / projection / readout ----------------
__global__ void pool_kernel(const float* __restrict__ hv_f32, const int* __restrict__ batch_id,
                            float* __restrict__ ge) {
    int col = threadIdx.x;  // 128 threads
    int base = blockIdx.x * 128;
    if (base >= NN) return;
    int end = base + 128; if (end > NN) end = NN;
    int cur = batch_id[base];
    float sum = 0.f;
    for (int g = base; g < end; g++) {
        int b = batch_id[g];
        if (b != cur) { atomicAdd(&ge[cur * 128 + col], sum); sum = 0.f; cur = b; }
        sum += hv_f32[(size_t)g * 128 + col];
    }
    atomicAdd(&ge[cur * 128 + col], sum);
}

__global__ void proj_kernel(const float* __restrict__ ge, const int* __restrict__ batch_id,
                            const void* __restrict__ P1, const void* __restrict__ P2,
                            const void* __restrict__ p2b, void* __restrict__ d_out,
                            const int* __restrict__ flag) {
    __shared__ float cnt[BBATCH];
    __shared__ float gm[BBATCH * HH];
    __shared__ float hb[BBATCH * HH];
    int t = threadIdx.x;
    const int f = flag[0];
    if (t < BBATCH) cnt[t] = 0.f;
    __syncthreads();
    for (int n = t; n < NN; n += 256) atomicAdd(&cnt[batch_id[n]], 1.0f);
    __syncthreads();
    for (int idx = t; idx < BBATCH * HH; idx += 256) {
        int b = idx >> 7;
        float c = cnt[b]; c = c < 1.f ? 1.f : c;
        gm[idx] = ge[idx] / c;
    }
    __syncthreads();
    for (int idx = t; idx < BBATCH * HH; idx += 256) {
        int b = idx >> 7, j = idx & 127;
        float s = 0.f;
        for (int k = 0; k < HH; k++) s += gm[b * 128 + k] * loadf(P1, k * 128 + j, f);
        hb[idx] = s > 0.f ? s : 0.f;
    }
    __syncthreads();
    for (int idx = t; idx < BBATCH * HH; idx += 256) {
        int b = idx >> 7, j = idx & 127;
        float s = loadf(p2b, j, f);
        for (int k = 0; k < HH; k++) s += hb[b * 128 + k] * loadf(P2, k * 128 + j, f);
        size_t o = (size_t)NN * VV + NN + idx;   // after logits + S
        if (f) ((float*)d_out)[o] = s;
        else   ((unsigned short*)d_out)[o] = f2bf(s);
    }
}

__global__ void logits_kernel(const float* __restrict__ hv_f32, const void* __restrict__ R,
                              const void* __restrict__ rb, const int* __restrict__ S,
                              void* __restrict__ d_out, const int* __restrict__ flag) {
    __shared__ float Rs[HH * VV];
    __shared__ float rbs[VV];
    int t = threadIdx.x;
    const int f = flag[0];
    for (int i = t; i < HH * VV; i += 256) Rs[i] = loadf(R, i, f);
    if (t < VV) rbs[t] = loadf(rb, t, f);
    __syncthreads();
    int g = blockIdx.x * 256 + t;
    if (g < NN) {
        float a0 = rbs[0], a1 = rbs[1], a2 = rbs[2], a3 = rbs[3];
        const float* hv = hv_f32 + (size_t)g * 128;
        for (int k = 0; k < 128; k++) {
            float h = hv[k];
            a0 += h * Rs[k * 4 + 0];
            a1 += h * Rs[k * 4 + 1];
            a2 += h * Rs[k * 4 + 2];
            a3 += h * Rs[k * 4 + 3];
        }
        float sv = (float)S[g];
        if (f) {
            float* o = (float*)d_out;
            o[g * 4 + 0] = a0; o[g * 4 + 1] = a1; o[g * 4 + 2] = a2; o[g * 4 + 3] = a3;
            o[(size_t)NN * VV + g] = sv;
        } else {
            unsigned short* o = (unsigned short*)d_out;
            o[g * 4 + 0] = f2bf(a0); o[g * 4 + 1] = f2bf(a1);
            o[g * 4 + 2] = f2bf(a2); o[g * 4 + 3] = f2bf(a3);
            o[(size_t)NN * VV + g] = f2bf(sv);
        }
    }
}

extern "C" void kernel_launch(void* const* d_in, const int* in_sizes, int n_in,
                              void* d_out, int out_size, void* d_ws, size_t ws_size,
                              hipStream_t stream) {
    const void* hV   = d_in[0];
    const void* hE   = d_in[1];
    const int*  Eidx = (const int*)d_in[2];
    const int*  bid  = (const int*)d_in[3];
    const int*  S    = (const int*)d_in[4];
    const void* W1   = d_in[5];
    const void* b1   = d_in[6];
    const void* W2   = d_in[7];
    const void* b2   = d_in[8];
    const void* W3   = d_in[9];
    const void* b3   = d_in[10];
    const void* ln1g = d_in[11];
    const void* ln1b = d_in[12];
    const void* Wi   = d_in[13];
    const void* bi   = d_in[14];
    const void* Wo   = d_in[15];
    const void* bo   = d_in[16];
    const void* ln2g = d_in[17];
    const void* ln2b = d_in[18];
    const void* P1   = d_in[19];
    const void* P2   = d_in[20];
    const void* p2b  = d_in[21];
    const void* R    = d_in[22];
    const void* rb   = d_in[23];

    char* ws = (char*)d_ws;
    float* hv_f32 = (float*)ws;           ws += (size_t)NN * HH * 4;
    float* agg    = (float*)ws;           ws += (size_t)NN * HH * 4;
    float* deg    = (float*)ws;           ws += (size_t)NN * 4;
    float* ge     = (float*)ws;           ws += (size_t)BBATCH * HH * 4;
    unsigned short* hv_bf = (unsigned short*)ws; ws += (size_t)NN * HH * 2;
    unsigned short* W1p   = (unsigned short*)ws; ws += (size_t)LL * 384 * 128 * 2;
    unsigned short* W2p   = (unsigned short*)ws; ws += (size_t)LL * 128 * 128 * 2;
    unsigned short* W3p   = (unsigned short*)ws; ws += (size_t)LL * 128 * 128 * 2;
    unsigned short* Wip   = (unsigned short*)ws; ws += (size_t)LL * 128 * 512 * 2;
    unsigned short* Wop   = (unsigned short*)ws; ws += (size_t)LL * 512 * 128 * 2;
    int* flag = (int*)ws;                 ws += 16;

    hipMemsetAsync(deg, 0, (size_t)NN * 4, stream);
    hipMemsetAsync(ge, 0, (size_t)BBATCH * HH * 4, stream);

    detect_kernel<<<1, 256, 0, stream>>>(hV, flag);

    init_hv_kernel<<<(NN * HH + 255) / 256, 256, 0, stream>>>(hV, hv_f32, hv_bf, NN * HH, flag);
    deg_kernel<<<(EE + 255) / 256, 256, 0, stream>>>(Eidx, deg);

    repack_kernel<<<(LL * 384 * 128 + 255) / 256, 256, 0, stream>>>(W1, W1p, 384, 128, LL * 384 * 128, flag);
    repack_kernel<<<(LL * 128 * 128 + 255) / 256, 256, 0, stream>>>(W2, W2p, 128, 128, LL * 128 * 128, flag);
    repack_kernel<<<(LL * 128 * 128 + 255) / 256, 256, 0, stream>>>(W3, W3p, 128, 128, LL * 128 * 128, flag);
    repack_kernel<<<(LL * 128 * 512 + 255) / 256, 256, 0, stream>>>(Wi, Wip, 128, 512, LL * 128 * 512, flag);
    repack_kernel<<<(LL * 512 * 128 + 255) / 256, 256, 0, stream>>>(Wo, Wop, 512, 128, LL * 512 * 128, flag);

    for (int i = 0; i < LL; i++) {
        hipMemsetAsync(agg, 0, (size_t)NN * HH * 4, stream);
        edge_kernel<<<EE / 64, 256, 0, stream>>>(hE, hv_bf, Eidx, W1p, b1, W2p, b2, W3p, b3, agg, i, flag);
        node_kernel<<<(NN + 63) / 64, 256, 0, stream>>>(hv_f32, hv_bf, agg, deg,
                                                        ln1g, ln1b, Wip, bi, Wop, bo, ln2g, ln2b, i, flag);
    }

    pool_kernel<<<(NN + 127) / 128, 128, 0, stream>>>(hv_f32, bid, ge);
    proj_kernel<<<1, 256, 0, stream>>>(ge, bid, P1, P2, p2b, d_out, flag);
    logits_kernel<<<(NN + 255) / 256, 256, 0, stream>>>(hv_f32, R, rb, S, d_out, flag);
}

// Round 3
// 3207.017 us; speedup vs baseline: 1.1331x; 1.1331x over previous
//
#include <hip/hip_runtime.h>
#include <stdint.h>

#define NN 20000
#define EE 600000
#define EP 600064   // EE padded to 128-edge blocks
#define HH 128
#define LL 6
#define BBATCH 16
#define VV 4

typedef __bf16 bf16x8 __attribute__((ext_vector_type(8)));
typedef float f32x4 __attribute__((ext_vector_type(4)));
typedef float f32x16 __attribute__((ext_vector_type(16)));

__device__ __forceinline__ float bf2f(unsigned short u) {
    union { uint32_t i; float f; } v; v.i = ((uint32_t)u) << 16; return v.f;
}
__device__ __forceinline__ unsigned short f2bf(float f) {
    union { float f; uint32_t i; } v; v.f = f;
    uint32_t u = v.i;
    return (unsigned short)((u + 0x7FFFu + ((u >> 16) & 1u)) >> 16);
}
__device__ __forceinline__ float loadf(const void* p, size_t i, int f) {
    return f ? ((const float*)p)[i] : bf2f(((const unsigned short*)p)[i]);
}
__device__ __forceinline__ void load8bf(const void* base, size_t elem, int f, unsigned short* o) {
    if (!f) {
        *(uint4*)o = *(const uint4*)((const unsigned short*)base + elem);
    } else {
        const float* p = (const float*)base + elem;
        float4 a = *(const float4*)p, b = *(const float4*)(p + 4);
        o[0] = f2bf(a.x); o[1] = f2bf(a.y); o[2] = f2bf(a.z); o[3] = f2bf(a.w);
        o[4] = f2bf(b.x); o[5] = f2bf(b.y); o[6] = f2bf(b.z); o[7] = f2bf(b.w);
    }
}

// ---- dtype sniffer (unchanged — validated in R2) ----
__global__ void detect_kernel(const void* hv, int* flag) {
    __shared__ int cnt;
    if (threadIdx.x == 0) cnt = 0;
    __syncthreads();
    const unsigned short* u = (const unsigned short*)hv;
    int local = 0;
    for (int i = threadIdx.x; i < 4096; i += 256) {
        unsigned short v = u[i];
        int e = (v >> 7) & 0xFF;
        if ((v & 0x7FFF) == 0 || (e >= 0x30 && e <= 0x85)) local++;
    }
    atomicAdd(&cnt, local);
    __syncthreads();
    if (threadIdx.x == 0) flag[0] = (cnt < 3500) ? 1 : 0;  // 1 = f32 world
}

// ---- weight pack [K][N] -> [K/16][N][16] (for 32x32x16 A/B frags) ----
__global__ void pack16_kernel(const void* __restrict__ src, unsigned short* __restrict__ dst,
                              int K, int Nc, int total, const int* __restrict__ flag) {
    int idx = blockIdx.x * blockDim.x + threadIdx.x;
    if (idx >= total) return;
    const int f = flag[0];
    int per = K * Nc;
    int layer = idx / per, rem = idx % per;
    int k = rem / Nc, n = rem % Nc;
    dst[(size_t)layer * per + ((size_t)(k >> 4) * Nc + n) * 16 + (k & 15)] = f2bf(loadf(src, idx, f));
}

// ---- weight pack [K][N] -> [K/32][N][32] (16x16x32 path, node kernel) ----
__global__ void repack32_kernel(const void* __restrict__ src, unsigned short* __restrict__ dst,
                                int K, int Nc, int total, const int* __restrict__ flag) {
    int idx = blockIdx.x * blockDim.x + threadIdx.x;
    if (idx >= total) return;
    const int f = flag[0];
    int per = K * Nc;
    int layer = idx / per, rem = idx % per;
    int k = rem / Nc, n = rem % Nc;
    dst[(size_t)layer * per + ((size_t)(k >> 5) * Nc + n) * 32 + (k & 31)] = f2bf(loadf(src, idx, f));
}

__global__ void init_hv_kernel(const void* __restrict__ hv_in, float* __restrict__ hv_f32,
                               unsigned short* __restrict__ hv_bf, int total,
                               const int* __restrict__ flag) {
    int idx = blockIdx.x * blockDim.x + threadIdx.x;
    if (idx >= total) return;
    const int f = flag[0];
    float v = loadf(hv_in, idx, f);
    hv_bf[idx] = f2bf(v);
    hv_f32[idx] = v;
}

// ---- counting sort of edges by src ----
__global__ void deg_kernel(const int* __restrict__ Eidx, int* __restrict__ degi) {
    int e = blockIdx.x * blockDim.x + threadIdx.x;
    if (e < EE) atomicAdd(&degi[Eidx[e]], 1);
}

__global__ void prefix_kernel(const int* __restrict__ degi, int* __restrict__ cursor,
                              float* __restrict__ degf) {
    __shared__ int part[256];
    __shared__ int psum[256];
    int t = threadIdx.x;
    const int CH = (NN + 255) / 256;
    int lo = t * CH, hi = lo + CH; if (hi > NN) hi = NN;
    int s = 0;
    for (int i = lo; i < hi; i++) s += degi[i];
    part[t] = s;
    __syncthreads();
    if (t == 0) {
        int run = 0;
        for (int i = 0; i < 256; i++) { psum[i] = run; run += part[i]; }
    }
    __syncthreads();
    int run = psum[t];
    for (int i = lo; i < hi; i++) {
        cursor[i] = run;
        run += degi[i];
        degf[i] = (float)degi[i];
    }
}

__global__ void perm_kernel(const int* __restrict__ Eidx, int* __restrict__ cursor,
                            int* __restrict__ perm) {
    int e = blockIdx.x * blockDim.x + threadIdx.x;
    if (e < EE) {
        int pos = atomicAdd(&cursor[Eidx[e]], 1);
        perm[pos] = e;
    }
}

__global__ void idx_kernel(const int* __restrict__ Eidx, const int* __restrict__ perm,
                           int* __restrict__ srcs_s, int* __restrict__ dsts_s) {
    int i = blockIdx.x * blockDim.x + threadIdx.x;
    if (i >= EP) return;
    if (i < EE) {
        int e = perm[i];
        srcs_s[i] = Eidx[e];
        dsts_s[i] = Eidx[EE + e];
    } else {
        srcs_s[i] = NN;   // dump row
        dsts_s[i] = 0;
    }
}

// permuted bf16 copy of h_E (only when ws allows)
__global__ void hep_kernel(const void* __restrict__ hE, const int* __restrict__ perm,
                           unsigned short* __restrict__ hEp, const int* __restrict__ flag) {
    int idx = blockIdx.x * blockDim.x + threadIdx.x;  // over EP*16
    if (idx >= EP * 16) return;
    int i = idx >> 4, p = idx & 15;
    unsigned short tmp[8];
    if (i < EE) {
        int e = perm[i];
        load8bf(hE, (size_t)e * 128 + p * 8, flag[0], tmp);
    } else {
        for (int j = 0; j < 8; j++) tmp[j] = 0;
    }
    *(uint4*)&hEp[(size_t)i * 128 + p * 8] = *(uint4*)tmp;
}

// ---------------- edge MLP v2: barrier-free, 32x32x16, sorted edges ----------------
// Wave owns 32 sorted edges x all 128 cols. GEMM1/2 transposed (W^T as A, X as B),
// m1/m2 wave-private LDS. GEMM3 standard orientation -> register segmented combine -> atomics.
__launch_bounds__(256, 2)
__global__ void edge_kernel(const void* __restrict__ hE, const unsigned short* __restrict__ hEp,
                            const int* __restrict__ perm,
                            const unsigned short* __restrict__ hv_bf,
                            const int* __restrict__ srcs_s, const int* __restrict__ dsts_s,
                            const unsigned short* __restrict__ W1a, const void* __restrict__ b1,
                            const unsigned short* __restrict__ W2a, const void* __restrict__ b2,
                            const unsigned short* __restrict__ W3b, const void* __restrict__ b3,
                            float* __restrict__ agg, int layer, const int* __restrict__ flag,
                            int use_hep) {
    __shared__ __align__(16) unsigned short lds[4 * 8704];
    const int t = threadIdx.x;
    const int w = t >> 6;
    const int ln5 = t & 31;
    const int q2 = (t >> 5) & 1;
    unsigned short* m1 = lds + w * 8704;          // [32][136]
    unsigned short* m2 = m1 + 4352;               // [32][136]
    const int f = flag[0];
    const int e0w = blockIdx.x * 128 + w * 32;
    const int edge = e0w + ln5;

    const int sidx = srcs_s[edge];
    const int didx = dsts_s[edge];
    int pe = 0;
    if (!use_hep && edge < EE) pe = perm[edge];

    const unsigned short* W1l = W1a + (size_t)layer * 384 * 128;
    const unsigned short* W2l = W2a + (size_t)layer * 128 * 128;
    const unsigned short* W3l = W3b + (size_t)layer * 128 * 128;

    f32x16 acc[4];

    // ================= GEMM1: m1^T = W1^T @ hEV^T =================
#pragma unroll
    for (int ct = 0; ct < 4; ct++)
#pragma unroll
        for (int r = 0; r < 16; r++) {
            int m = 32 * ct + (r & 3) + 8 * (r >> 2) + 4 * q2;
            acc[ct][r] = loadf(b1, (size_t)layer * 128 + m, f);
        }

    // K segment 1: h_E (kk 0..7)
#pragma unroll
    for (int kk = 0; kk < 8; kk++) {
        bf16x8 bB;
        if (use_hep) {
            bB = *(const bf16x8*)&hEp[(size_t)edge * 128 + kk * 16 + q2 * 8];
        } else if (!f) {
            bB = *(const bf16x8*)&((const unsigned short*)hE)[(size_t)pe * 128 + kk * 16 + q2 * 8];
        } else {
            unsigned short tmp[8];
            load8bf(hE, (size_t)pe * 128 + kk * 16 + q2 * 8, 1, tmp);
            bB = *(bf16x8*)tmp;
        }
#pragma unroll
        for (int ct = 0; ct < 4; ct++) {
            bf16x8 aA = *(const bf16x8*)&W1l[((size_t)(kk * 128 + 32 * ct + ln5)) * 16 + q2 * 8];
            acc[ct] = __builtin_amdgcn_mfma_f32_32x32x16_bf16(aA, bB, acc[ct], 0, 0, 0);
        }
    }
    // K segment 2: h_V[src] (kk 8..15)
#pragma unroll
    for (int kk = 0; kk < 8; kk++) {
        bf16x8 bB = *(const bf16x8*)&hv_bf[(size_t)sidx * 128 + kk * 16 + q2 * 8];
#pragma unroll
        for (int ct = 0; ct < 4; ct++) {
            bf16x8 aA = *(const bf16x8*)&W1l[((size_t)((kk + 8) * 128 + 32 * ct + ln5)) * 16 + q2 * 8];
            acc[ct] = __builtin_amdgcn_mfma_f32_32x32x16_bf16(aA, bB, acc[ct], 0, 0, 0);
        }
    }
    // K segment 3: h_V[dst] (kk 16..23)
#pragma unroll
    for (int kk = 0; kk < 8; kk++) {
        bf16x8 bB = *(const bf16x8*)&hv_bf[(size_t)didx * 128 + kk * 16 + q2 * 8];
#pragma unroll
        for (int ct = 0; ct < 4; ct++) {
            bf16x8 aA = *(const bf16x8*)&W1l[((size_t)((kk + 16) * 128 + 32 * ct + ln5)) * 16 + q2 * 8];
            acc[ct] = __builtin_amdgcn_mfma_f32_32x32x16_bf16(aA, bB, acc[ct], 0, 0, 0);
        }
    }
    // relu + store m1[edge][mcol] (b64-packed; wave-private, no barrier)
#pragma unroll
    for (int ct = 0; ct < 4; ct++)
#pragma unroll
        for (int g = 0; g < 4; g++) {
            uint2 u;
            unsigned short* tp = (unsigned short*)&u;
#pragma unroll
            for (int r = 0; r < 4; r++) {
                float x = acc[ct][4 * g + r];
                tp[r] = f2bf(x > 0.f ? x : 0.f);
            }
            *(uint2*)&m1[ln5 * 136 + 32 * ct + 8 * g + 4 * q2] = u;
        }

    // ================= GEMM2: m2^T = W2^T @ m1^T =================
#pragma unroll
    for (int ct = 0; ct < 4; ct++)
#pragma unroll
        for (int r = 0; r < 16; r++) {
            int m = 32 * ct + (r & 3) + 8 * (r >> 2) + 4 * q2;
            acc[ct][r] = loadf(b2, (size_t)layer * 128 + m, f);
        }
#pragma unroll
    for (int kk = 0; kk < 8; kk++) {
        bf16x8 bB = *(const bf16x8*)&m1[ln5 * 136 + kk * 16 + q2 * 8];
#pragma unroll
        for (int ct = 0; ct < 4; ct++) {
            bf16x8 aA = *(const bf16x8*)&W2l[((size_t)(kk * 128 + 32 * ct + ln5)) * 16 + q2 * 8];
            acc[ct] = __builtin_amdgcn_mfma_f32_32x32x16_bf16(aA, bB, acc[ct], 0, 0, 0);
        }
    }
#pragma unroll
    for (int ct = 0; ct < 4; ct++)
#pragma unroll
        for (int g = 0; g < 4; g++) {
            uint2 u;
            unsigned short* tp = (unsigned short*)&u;
#pragma unroll
            for (int r = 0; r < 4; r++) {
                float x = acc[ct][4 * g + r];
                tp[r] = f2bf(x > 0.f ? x : 0.f);
            }
            *(uint2*)&m2[ln5 * 136 + 32 * ct + 8 * g + 4 * q2] = u;
        }

    // ================= GEMM3 (standard): C3 = m2 @ W3 =================
#pragma unroll
    for (int c = 0; c < 4; c++) {
        float bv = loadf(b3, (size_t)layer * 128 + 32 * c + ln5, f);
#pragma unroll
        for (int r = 0; r < 16; r++) acc[c][r] = bv;
    }
#pragma unroll
    for (int kk = 0; kk < 8; kk++) {
        bf16x8 aA = *(const bf16x8*)&m2[ln5 * 136 + kk * 16 + q2 * 8];  // A: rows=edges
#pragma unroll
        for (int c = 0; c < 4; c++) {
            bf16x8 bB = *(const bf16x8*)&W3l[((size_t)(kk * 128 + 32 * c + ln5)) * 16 + q2 * 8];
            acc[c] = __builtin_amdgcn_mfma_f32_32x32x16_bf16(aA, bB, acc[c], 0, 0, 0);
        }
    }

    // ---- register segmented combine over 4 consecutive sorted edges, then atomics ----
    int sg[4][4];
#pragma unroll
    for (int g = 0; g < 4; g++)
#pragma unroll
        for (int r = 0; r < 4; r++)
            sg[g][r] = srcs_s[e0w + 8 * g + 4 * q2 + r];

#pragma unroll
    for (int c = 0; c < 4; c++) {
        int col = 32 * c + ln5;
#pragma unroll
        for (int g = 0; g < 4; g++) {
            float a0 = acc[c][4 * g + 0], a1 = acc[c][4 * g + 1];
            float a2 = acc[c][4 * g + 2], a3 = acc[c][4 * g + 3];
            int s0 = sg[g][0], s1 = sg[g][1], s2 = sg[g][2], s3 = sg[g][3];
            if (s3 == s2) a2 += a3; else atomicAdd(&agg[(size_t)s3 * 128 + col], a3);
            if (s2 == s1) a1 += a2; else atomicAdd(&agg[(size_t)s2 * 128 + col], a2);
            if (s1 == s0) a0 += a1; else atomicAdd(&agg[(size_t)s1 * 128 + col], a1);
            atomicAdd(&agg[(size_t)s0 * 128 + col], a0);
        }
    }
}

// ---------------- node update: LN1 -> FFN -> LN2 (unchanged from R2) ----------------
__launch_bounds__(256, 1)
__global__ void node_kernel(float* __restrict__ hv_f32, unsigned short* __restrict__ hv_bf,
                            const float* __restrict__ agg, const float* __restrict__ deg,
                            const void* __restrict__ ln1g, const void* __restrict__ ln1b,
                            const unsigned short* __restrict__ Wip, const void* __restrict__ bip,
                            const unsigned short* __restrict__ Wop, const void* __restrict__ bop,
                            const void* __restrict__ ln2g, const void* __restrict__ ln2b,
                            int layer, const int* __restrict__ flag) {
    __shared__ __align__(16) float xf[64 * 132];
    __shared__ __align__(16) unsigned short tb[64 * 136];
    __shared__ __align__(16) unsigned short ub[64 * 520];
    const int t = threadIdx.x;
    const int w = t >> 6;
    const int lane = t & 63;
    const int q = lane >> 4, ln = lane & 15;
    const int n0 = blockIdx.x * 64;
    const int f = flag[0];

    for (int idx = t; idx < 64 * 128; idx += 256) {
        int row = idx >> 7, col = idx & 127;
        int g = n0 + row;
        float v = 0.f;
        if (g < NN) {
            float dg = deg[g]; dg = dg < 1.f ? 1.f : dg;
            v = hv_f32[(size_t)g * 128 + col] + agg[(size_t)g * 128 + col] / dg;
        }
        xf[row * 132 + col] = v;
    }
    __syncthreads();

    if (t < 64) {
        float mu = 0.f;
        for (int j = 0; j < 128; j++) mu += xf[t * 132 + j];
        mu *= (1.f / 128.f);
        float var = 0.f;
        for (int j = 0; j < 128; j++) { float d = xf[t * 132 + j] - mu; var += d * d; }
        var *= (1.f / 128.f);
        float rs = rsqrtf(var + 1e-5f);
        for (int j = 0; j < 128; j++) {
            float val = (xf[t * 132 + j] - mu) * rs * loadf(ln1g, layer * 128 + j, f)
                        + loadf(ln1b, layer * 128 + j, f);
            xf[t * 132 + j] = val;
            tb[t * 136 + j] = f2bf(val);
        }
    }
    __syncthreads();

    {
        const unsigned short* Wil = Wip + (size_t)layer * 128 * 512;
        for (int g2 = 0; g2 < 2; g2++) {
            f32x4 acc[4][4];
            for (int c = 0; c < 4; c++) {
                int ct = 8 * w + 4 * g2 + c;
                float bv = loadf(bip, (size_t)layer * 512 + 16 * ct + ln, f);
                for (int rt = 0; rt < 4; rt++) acc[rt][c] = (f32x4){bv, bv, bv, bv};
            }
            for (int kk = 0; kk < 4; kk++) {
                bf16x8 bfr[4];
                for (int c = 0; c < 4; c++) {
                    int ct = 8 * w + 4 * g2 + c;
                    bfr[c] = *(const bf16x8*)&Wil[((size_t)(kk * 512 + 16 * ct + ln)) * 32 + q * 8];
                }
                for (int rt = 0; rt < 4; rt++) {
                    bf16x8 af = *(bf16x8*)&tb[(16 * rt + ln) * 136 + kk * 32 + q * 8];
                    for (int c = 0; c < 4; c++)
                        acc[rt][c] = __builtin_amdgcn_mfma_f32_16x16x32_bf16(af, bfr[c], acc[rt][c], 0, 0, 0);
                }
            }
            for (int rt = 0; rt < 4; rt++)
                for (int c = 0; c < 4; c++) {
                    int ct = 8 * w + 4 * g2 + c;
                    for (int r = 0; r < 4; r++) {
                        float v = acc[rt][c][r]; v = v > 0.f ? v : 0.f;
                        ub[(16 * rt + q * 4 + r) * 520 + 16 * ct + ln] = f2bf(v);
                    }
                }
        }
    }
    __syncthreads();

    {
        const unsigned short* Wol = Wop + (size_t)layer * 512 * 128;
        f32x4 acc[4][2];
        for (int c = 0; c < 2; c++) {
            int ct = 2 * w + c;
            float bv = loadf(bop, (size_t)layer * 128 + 16 * ct + ln, f);
            for (int rt = 0; rt < 4; rt++) acc[rt][c] = (f32x4){bv, bv, bv, bv};
        }
        for (int kk = 0; kk < 16; kk++) {
            bf16x8 bfr[2];
            for (int c = 0; c < 2; c++) {
                int ct = 2 * w + c;
                bfr[c] = *(const bf16x8*)&Wol[((size_t)(kk * 128 + 16 * ct + ln)) * 32 + q * 8];
            }
            for (int rt = 0; rt < 4; rt++) {
                bf16x8 af = *(bf16x8*)&ub[(16 * rt + ln) * 520 + kk * 32 + q * 8];
                for (int c = 0; c < 2; c++)
                    acc[rt][c] = __builtin_amdgcn_mfma_f32_16x16x32_bf16(af, bfr[c], acc[rt][c], 0, 0, 0);
            }
        }
        for (int rt = 0; rt < 4; rt++)
            for (int c = 0; c < 2; c++) {
                int ct = 2 * w + c;
                for (int r = 0; r < 4; r++)
                    xf[(16 * rt + q * 4 + r) * 132 + 16 * ct + ln] += acc[rt][c][r];
            }
    }
    __syncthreads();

    if (t < 64) {
        int g = n0 + t;
        if (g < NN) {
            float mu = 0.f;
            for (int j = 0; j < 128; j++) mu += xf[t * 132 + j];
            mu *= (1.f / 128.f);
            float var = 0.f;
            for (int j = 0; j < 128; j++) { float d = xf[t * 132 + j] - mu; var += d * d; }
            var *= (1.f / 128.f);
            float rs = rsqrtf(var + 1e-5f);
            for (int j = 0; j < 128; j++) {
                float val = (xf[t * 132 + j] - mu) * rs * loadf(ln2g, layer * 128 + j, f)
                            + loadf(ln2b, layer * 128 + j, f);
                hv_f32[(size_t)g * 128 + j] = val;
                hv_bf[(size_t)g * 128 + j] = f2bf(val);
            }
        }
    }
}

// ---------------- pooling / projection / readout (unchanged) ----------------
__global__ void pool_kernel(const float* __restrict__ hv_f32, const int* __restrict__ batch_id,
                            float* __restrict__ ge) {
    int col = threadIdx.x;
    int base = blockIdx.x * 128;
    if (base >= NN) return;
    int end = base + 128; if (end > NN) end = NN;
    int cur = batch_id[base];
    float sum = 0.f;
    for (int g = base; g < end; g++) {
        int b = batch_id[g];
        if (b != cur) { atomicAdd(&ge[cur * 128 + col], sum); sum = 0.f; cur = b; }
        sum += hv_f32[(size_t)g * 128 + col];
    }
    atomicAdd(&ge[cur * 128 + col], sum);
}

__global__ void proj_kernel(const float* __restrict__ ge, const int* __restrict__ batch_id,
                            const void* __restrict__ P1, const void* __restrict__ P2,
                            const void* __restrict__ p2b, void* __restrict__ d_out,
                            const int* __restrict__ flag) {
    __shared__ float cnt[BBATCH];
    __shared__ float gm[BBATCH * HH];
    __shared__ float hb[BBATCH * HH];
    int t = threadIdx.x;
    const int f = flag[0];
    if (t < BBATCH) cnt[t] = 0.f;
    __syncthreads();
    for (int n = t; n < NN; n += 256) atomicAdd(&cnt[batch_id[n]], 1.0f);
    __syncthreads();
    for (int idx = t; idx < BBATCH * HH; idx += 256) {
        int b = idx >> 7;
        float c = cnt[b]; c = c < 1.f ? 1.f : c;
        gm[idx] = ge[idx] / c;
    }
    __syncthreads();
    for (int idx = t; idx < BBATCH * HH; idx += 256) {
        int b = idx >> 7, j = idx & 127;
        float s = 0.f;
        for (int k = 0; k < HH; k++) s += gm[b * 128 + k] * loadf(P1, k * 128 + j, f);
        hb[idx] = s > 0.f ? s : 0.f;
    }
    __syncthreads();
    for (int idx = t; idx < BBATCH * HH; idx += 256) {
        int b = idx >> 7, j = idx & 127;
        float s = loadf(p2b, j, f);
        for (int k = 0; k < HH; k++) s += hb[b * 128 + k] * loadf(P2, k * 128 + j, f);
        size_t o = (size_t)NN * VV + NN + idx;
        if (f) ((float*)d_out)[o] = s;
        else   ((unsigned short*)d_out)[o] = f2bf(s);
    }
}

__global__ void logits_kernel(const float* __restrict__ hv_f32, const void* __restrict__ R,
                              const void* __restrict__ rb, const int* __restrict__ S,
                              void* __restrict__ d_out, const int* __restrict__ flag) {
    __shared__ float Rs[HH * VV];
    __shared__ float rbs[VV];
    int t = threadIdx.x;
    const int f = flag[0];
    for (int i = t; i < HH * VV; i += 256) Rs[i] = loadf(R, i, f);
    if (t < VV) rbs[t] = loadf(rb, t, f);
    __syncthreads();
    int g = blockIdx.x * 256 + t;
    if (g < NN) {
        float a0 = rbs[0], a1 = rbs[1], a2 = rbs[2], a3 = rbs[3];
        const float* hv = hv_f32 + (size_t)g * 128;
        for (int k = 0; k < 128; k++) {
            float h = hv[k];
            a0 += h * Rs[k * 4 + 0];
            a1 += h * Rs[k * 4 + 1];
            a2 += h * Rs[k * 4 + 2];
            a3 += h * Rs[k * 4 + 3];
        }
        float sv = (float)S[g];
        if (f) {
            float* o = (float*)d_out;
            o[g * 4 + 0] = a0; o[g * 4 + 1] = a1; o[g * 4 + 2] = a2; o[g * 4 + 3] = a3;
            o[(size_t)NN * VV + g] = sv;
        } else {
            unsigned short* o = (unsigned short*)d_out;
            o[g * 4 + 0] = f2bf(a0); o[g * 4 + 1] = f2bf(a1);
            o[g * 4 + 2] = f2bf(a2); o[g * 4 + 3] = f2bf(a3);
            o[(size_t)NN * VV + g] = f2bf(sv);
        }
    }
}

extern "C" void kernel_launch(void* const* d_in, const int* in_sizes, int n_in,
                              void* d_out, int out_size, void* d_ws, size_t ws_size,
                              hipStream_t stream) {
    const void* hV   = d_in[0];
    const void* hE   = d_in[1];
    const int*  Eidx = (const int*)d_in[2];
    const int*  bid  = (const int*)d_in[3];
    const int*  S    = (const int*)d_in[4];
    const void* W1   = d_in[5];
    const void* b1   = d_in[6];
    const void* W2   = d_in[7];
    const void* b2   = d_in[8];
    const void* W3   = d_in[9];
    const void* b3   = d_in[10];
    const void* ln1g = d_in[11];
    const void* ln1b = d_in[12];
    const void* Wi   = d_in[13];
    const void* bi   = d_in[14];
    const void* Wo   = d_in[15];
    const void* bo   = d_in[16];
    const void* ln2g = d_in[17];
    const void* ln2b = d_in[18];
    const void* P1   = d_in[19];
    const void* P2   = d_in[20];
    const void* p2b  = d_in[21];
    const void* R    = d_in[22];
    const void* rb   = d_in[23];

    char* ws = (char*)d_ws;
    float* hv_f32 = (float*)ws;                   ws += (size_t)NN * HH * 4;
    float* agg    = (float*)ws;                   ws += (size_t)(NN + 1) * HH * 4;
    float* degf   = (float*)ws;                   ws += (size_t)NN * 4;
    float* ge     = (float*)ws;                   ws += (size_t)BBATCH * HH * 4;
    unsigned short* hv_bf = (unsigned short*)ws;  ws += (size_t)(NN + 1) * HH * 2;
    unsigned short* W1a   = (unsigned short*)ws;  ws += (size_t)LL * 384 * 128 * 2;
    unsigned short* W2a   = (unsigned short*)ws;  ws += (size_t)LL * 128 * 128 * 2;
    unsigned short* W3b   = (unsigned short*)ws;  ws += (size_t)LL * 128 * 128 * 2;
    unsigned short* Wip   = (unsigned short*)ws;  ws += (size_t)LL * 128 * 512 * 2;
    unsigned short* Wop   = (unsigned short*)ws;  ws += (size_t)LL * 512 * 128 * 2;
    int* degi   = (int*)ws;                       ws += (size_t)NN * 4;
    int* cursor = (int*)ws;                       ws += (size_t)NN * 4;
    int* perm   = (int*)ws;                       ws += (size_t)EP * 4;
    int* srcs_s = (int*)ws;                       ws += (size_t)EP * 4;
    int* dsts_s = (int*)ws;                       ws += (size_t)EP * 4;
    int* flag   = (int*)ws;                       ws += 16;
    unsigned short* hEp = (unsigned short*)ws;
    size_t need_hep = (size_t)(ws - (char*)d_ws) + (size_t)EP * 128 * 2;
    int use_hep = (ws_size >= need_hep) ? 1 : 0;

    hipMemsetAsync(degi, 0, (size_t)NN * 4, stream);
    hipMemsetAsync(ge, 0, (size_t)BBATCH * HH * 4, stream);

    detect_kernel<<<1, 256, 0, stream>>>(hV, flag);

    init_hv_kernel<<<(NN * HH + 255) / 256, 256, 0, stream>>>(hV, hv_f32, hv_bf, NN * HH, flag);
    deg_kernel<<<(EE + 255) / 256, 256, 0, stream>>>(Eidx, degi);
    prefix_kernel<<<1, 256, 0, stream>>>(degi, cursor, degf);
    perm_kernel<<<(EE + 255) / 256, 256, 0, stream>>>(Eidx, cursor, perm);
    idx_kernel<<<(EP + 255) / 256, 256, 0, stream>>>(Eidx, perm, srcs_s, dsts_s);
    if (use_hep)
        hep_kernel<<<(EP * 16 + 255) / 256, 256, 0, stream>>>(hE, perm, hEp, flag);

    pack16_kernel<<<(LL * 384 * 128 + 255) / 256, 256, 0, stream>>>(W1, W1a, 384, 128, LL * 384 * 128, flag);
    pack16_kernel<<<(LL * 128 * 128 + 255) / 256, 256, 0, stream>>>(W2, W2a, 128, 128, LL * 128 * 128, flag);
    pack16_kernel<<<(LL * 128 * 128 + 255) / 256, 256, 0, stream>>>(W3, W3b, 128, 128, LL * 128 * 128, flag);
    repack32_kernel<<<(LL * 128 * 512 + 255) / 256, 256, 0, stream>>>(Wi, Wip, 128, 512, LL * 128 * 512, flag);
    repack32_kernel<<<(LL * 512 * 128 + 255) / 256, 256, 0, stream>>>(Wo, Wop, 512, 128, LL * 512 * 128, flag);

    for (int i = 0; i < LL; i++) {
        hipMemsetAsync(agg, 0, (size_t)(NN + 1) * HH * 4, stream);
        edge_kernel<<<EP / 128, 256, 0, stream>>>(hE, hEp, perm, hv_bf, srcs_s, dsts_s,
                                                  W1a, b1, W2a, b2, W3b, b3, agg, i, flag, use_hep);
        node_kernel<<<(NN + 63) / 64, 256, 0, stream>>>(hv_f32, hv_bf, agg, degf,
                                                        ln1g, ln1b, Wip, bi, Wop, bo, ln2g, ln2b, i, flag);
    }

    pool_kernel<<<(NN + 127) / 128, 128, 0, stream>>>(hv_f32, bid, ge);
    proj_kernel<<<1, 256, 0, stream>>>(ge, bid, P1, P2, p2b, d_out, flag);
    logits_kernel<<<(NN + 255) / 256, 256, 0, stream>>>(hv_f32, R, rb, S, d_out, flag);
}